// Round 2
// baseline (356.289 us; speedup 1.0000x reference)
//
#include <hip/hip_runtime.h>
#include <hip/hip_bf16.h>

// MHA block: x[4096,1024] fp32; Wq/Wk/Wv/Wo [1024,1024] fp32.
// R12: attention with ZERO LDS / ZERO barriers.
//  K/V per head are L2-resident (2 heads/XCD = 2MB of 4MB L2) -> LDS staging
//  was pure overhead (41us of ds_read_b128 pipe + per-step barrier drains).
//  Fragments now load straight from global (fully coalesced 16x64B lines),
//  manually software-pipelined (fA/fB named double-buffer, no runtime
//  indexing) across the barrier-free 64-step loop. Output stored directly
//  from fragments (1/l is lane-local). Attn kernel has no __shared__ and no
//  __syncthreads at all.
// Keeps: 256-thr/4-wave/32-rows-per-wave proven geometry, magic-mantissa
//  Schraudolph exp2 (R11), S^T trick, MFMA l-sums, key-interleaved V^T,
//  R6 GEMMs/casts.

typedef __bf16 bf16_t;
typedef __bf16 bf16x8 __attribute__((ext_vector_type(8)));
typedef __bf16 bf16x4 __attribute__((ext_vector_type(4)));
typedef float f32x4 __attribute__((ext_vector_type(4)));

#define D_MODEL 1024
#define SEQ 4096
#define HEADS 16
#define DK 64
#define QSCALE 0.1803368801111204f  // log2(e)/8
#define EXP2_MAGIC 8404859.0f       // 2^23 + 16251 (integer-exact float)

// ---------------- casts fp32 -> bf16 ----------------
__global__ void cast_kernel(const float* __restrict__ in, bf16_t* __restrict__ out, int n) {
    int i = (blockIdx.x * blockDim.x + threadIdx.x) * 4;
    if (i < n) {
        float4 v = *(const float4*)(in + i);
        bf16x4 o;
        o[0] = (bf16_t)v.x; o[1] = (bf16_t)v.y; o[2] = (bf16_t)v.z; o[3] = (bf16_t)v.w;
        *(bf16x4*)(out + i) = o;
    }
}

__global__ void cast4_kernel(const float* __restrict__ a, const float* __restrict__ b,
                             const float* __restrict__ c, const float* __restrict__ d,
                             bf16_t* __restrict__ out) {
    int gi = blockIdx.x * blockDim.x + threadIdx.x;
    int which = gi >> 18;
    int i = (gi & 0x3FFFF) * 4;
    const float* src = which == 0 ? a : which == 1 ? b : which == 2 ? c : d;
    float4 v = *(const float4*)(src + i);
    bf16x4 o;
    o[0] = (bf16_t)v.x; o[1] = (bf16_t)v.y; o[2] = (bf16_t)v.z; o[3] = (bf16_t)v.w;
    *(bf16x4*)(out + (size_t)which * D_MODEL * D_MODEL + i) = o;
}

__device__ __forceinline__ void g2l16(const bf16_t* g, bf16_t* l) {
    __builtin_amdgcn_global_load_lds(
        (const __attribute__((address_space(1))) void*)g,
        (__attribute__((address_space(3))) void*)l, 16, 0, 0);
}

// Schraudolph exp2 -> packed bf16x8: slots 0-3 = 2^a[r], 4-7 = 2^b[r].
// fma into [2^23,2^24): low 16 float bits ARE the bf16 bits; v_perm packs.
__device__ __forceinline__ bf16x8 exp2_pk(const f32x4 a, const f32x4 b) {
    union { float f; unsigned u; } v[8];
#pragma unroll
    for (int r = 0; r < 4; r++) {
        v[r].f     = fmaf(a[r], 128.0f, EXP2_MAGIC);
        v[r + 4].f = fmaf(b[r], 128.0f, EXP2_MAGIC);
    }
    union { unsigned u[4]; bf16x8 h; } o;
#pragma unroll
    for (int p = 0; p < 4; p++)
        o.u[p] = __builtin_amdgcn_perm(v[2 * p + 1].u, v[2 * p].u, 0x05040100u);
    return o.h;
}

// ---------------- LDS-staged NT GEMM ----------------
// ROUTE 1: QKV split; V^T written key-interleaved (see header comment).
template <int ROUTE>
__global__ __launch_bounds__(256, 4) void gemm_lds(const bf16_t* __restrict__ A,
                                                   const bf16_t* __restrict__ B,
                                                   void* __restrict__ out0,
                                                   void* __restrict__ out1,
                                                   void* __restrict__ out2,
                                                   int M, int N, int K) {
    __shared__ __align__(16) bf16_t As[128 * 64];
    __shared__ __align__(16) bf16_t Bs[64 * 64];

    const int tid = threadIdx.x;
    const int lane = tid & 63;
    const int wave = tid >> 6;
    const int l15 = lane & 15;
    const int lg  = lane >> 4;
    const int m0 = blockIdx.y * 128;
    const int n0 = blockIdx.x * 64;
    const int wm = (wave >> 1) * 64;
    const int wn = (wave & 1) * 32;

    const bf16_t* aSrc[4]; bf16_t* aDst[4];
#pragma unroll
    for (int it = 0; it < 4; it++) {
        int c = it * 256 + tid;
        int row = c >> 3, cc = (c & 7) ^ (row & 7);
        aSrc[it] = A + (size_t)(m0 + row) * K + cc * 8;
        aDst[it] = As + c * 8;
    }
    const bf16_t* bSrc[2]; bf16_t* bDst[2];
#pragma unroll
    for (int it = 0; it < 2; it++) {
        int c = it * 256 + tid;
        int row = c >> 3, cc = (c & 7) ^ (row & 7);
        bSrc[it] = B + (size_t)(n0 + row) * K + cc * 8;
        bDst[it] = Bs + c * 8;
    }

    int aoff[2][4], boff[2][2];
#pragma unroll
    for (int kk = 0; kk < 2; kk++) {
#pragma unroll
        for (int i = 0; i < 4; i++) {
            int row = wm + i * 16 + l15;
            aoff[kk][i] = row * 64 + (((kk << 2) | lg) ^ (row & 7)) * 8;
        }
#pragma unroll
        for (int j = 0; j < 2; j++) {
            int row = wn + j * 16 + l15;
            boff[kk][j] = row * 64 + (((kk << 2) | lg) ^ (row & 7)) * 8;
        }
    }

    f32x4 acc[4][2];
#pragma unroll
    for (int i = 0; i < 4; i++)
#pragma unroll
        for (int j = 0; j < 2; j++) acc[i][j] = f32x4{0.f, 0.f, 0.f, 0.f};

    for (int k0 = 0; k0 < K; k0 += 64) {
#pragma unroll
        for (int it = 0; it < 4; it++) g2l16(aSrc[it] + k0, aDst[it]);
#pragma unroll
        for (int it = 0; it < 2; it++) g2l16(bSrc[it] + k0, bDst[it]);
        __syncthreads();

#pragma unroll
        for (int kk = 0; kk < 2; kk++) {
            bf16x8 af[4], bfm[2];
#pragma unroll
            for (int i = 0; i < 4; i++) af[i] = *(const bf16x8*)(As + aoff[kk][i]);
#pragma unroll
            for (int j = 0; j < 2; j++) bfm[j] = *(const bf16x8*)(Bs + boff[kk][j]);
#pragma unroll
            for (int i = 0; i < 4; i++)
#pragma unroll
                for (int j = 0; j < 2; j++)
                    acc[i][j] = __builtin_amdgcn_mfma_f32_16x16x32_bf16(af[i], bfm[j], acc[i][j], 0, 0, 0);
        }
        __syncthreads();
    }

    const int ng = n0 + wn;
    if (ROUTE == 0) {
        float* C = (float*)out0;
#pragma unroll
        for (int i = 0; i < 4; i++)
#pragma unroll
            for (int r = 0; r < 4; r++) {
                int m = m0 + wm + i * 16 + lg * 4 + r;
                float* crow = C + (size_t)m * N + ng;
#pragma unroll
                for (int j = 0; j < 2; j++) crow[j * 16 + l15] = acc[i][j][r];
            }
    } else {
        if (ng < 2048) {
            const bool isQ = (ng < 1024);
            const float sc = isQ ? QSCALE : 1.0f;
            bf16_t* dst = isQ ? (bf16_t*)out0 : (bf16_t*)out1;
            int nn = ng & 1023;
#pragma unroll
            for (int i = 0; i < 4; i++)
#pragma unroll
                for (int r = 0; r < 4; r++) {
                    int m = m0 + wm + i * 16 + lg * 4 + r;
                    bf16_t* crow = dst + (size_t)m * D_MODEL + nn;
#pragma unroll
                    for (int j = 0; j < 2; j++) crow[j * 16 + l15] = (bf16_t)(acc[i][j][r] * sc);
                }
        } else {
            bf16_t* Vt = (bf16_t*)out2;
#pragma unroll
            for (int i = 0; i < 4; i++)
#pragma unroll
                for (int j = 0; j < 2; j++) {
                    int vcol = ng - 2048 + j * 16 + l15;
                    int m = m0 + wm + i * 16 + lg * 4;  // multiple of 4
                    // key-interleave within 32-key block: pos = g*8 + sub*4 + r
                    int mp = (m & ~31) | (((m >> 2) & 3) << 3) | (((m >> 4) & 1) << 2);
                    bf16x4 v4;
#pragma unroll
                    for (int r = 0; r < 4; r++) v4[r] = (bf16_t)acc[i][j][r];
                    *(bf16x4*)(Vt + (size_t)vcol * SEQ + mp) = v4;
                }
        }
    }
}

// ---------------- attention: no LDS, no barriers, reg-pipelined -----------
struct Frags {
    bf16x8 kf[4][2];
    bf16x8 vf[2][4];
};

__device__ __forceinline__ void load_frags(Frags& f, const bf16_t* __restrict__ kB,
                                           const bf16_t* __restrict__ vB, int s) {
    const bf16_t* kS = kB + (size_t)s * 64 * D_MODEL;
    const bf16_t* vS = vB + (size_t)s * 64;
#pragma unroll
    for (int kt = 0; kt < 4; kt++)
#pragma unroll
        for (int c = 0; c < 2; c++)
            f.kf[kt][c] = *(const bf16x8*)(kS + (size_t)kt * 16 * D_MODEL + c * 32);
#pragma unroll
    for (int kp = 0; kp < 2; kp++)
#pragma unroll
        for (int dt = 0; dt < 4; dt++)
            f.vf[kp][dt] = *(const bf16x8*)(vS + (size_t)dt * 16 * SEQ + kp * 32);
}

__device__ __forceinline__ void compute_step(const Frags& f, const bf16x8 (&qf)[2][2],
                                             f32x4 (&oacc)[2][4], f32x4 (&lfrag)[2],
                                             const bf16x8 ones8) {
#pragma unroll
    for (int kp = 0; kp < 2; kp++) {
        f32x4 st[2][2];
#pragma unroll
        for (int sub = 0; sub < 2; sub++) {
            const int kt = kp * 2 + sub;
#pragma unroll
            for (int t = 0; t < 2; t++) {
                f32x4 a = f32x4{0.f, 0.f, 0.f, 0.f};
                a = __builtin_amdgcn_mfma_f32_16x16x32_bf16(f.kf[kt][0], qf[t][0], a, 0, 0, 0);
                a = __builtin_amdgcn_mfma_f32_16x16x32_bf16(f.kf[kt][1], qf[t][1], a, 0, 0, 0);
                st[t][sub] = a;
            }
        }
#pragma unroll
        for (int t = 0; t < 2; t++) {
            const bf16x8 pbig = exp2_pk(st[t][0], st[t][1]);
            lfrag[t] = __builtin_amdgcn_mfma_f32_16x16x32_bf16(ones8, pbig, lfrag[t], 0, 0, 0);
#pragma unroll
            for (int dt = 0; dt < 4; dt++)
                oacc[t][dt] = __builtin_amdgcn_mfma_f32_16x16x32_bf16(f.vf[kp][dt], pbig, oacc[t][dt], 0, 0, 0);
        }
    }
}

__global__ __launch_bounds__(256, 2) void attn_kernel(const bf16_t* __restrict__ Q,
                                                      const bf16_t* __restrict__ Km,
                                                      const bf16_t* __restrict__ Vt,
                                                      bf16_t* __restrict__ O) {
    const int tid = threadIdx.x;
    const int lane = tid & 63;
    const int wave = tid >> 6;   // 0..3, each owns 32 q-rows
    const int l15 = lane & 15;
    const int lg  = lane >> 4;
    const int bid = blockIdx.x;
    const int h    = (bid & 7) * 2 + ((bid >> 3) & 1);  // 2 heads per XCD -> K/V L2-resident
    const int qblk = bid >> 4;
    const int q0 = qblk * 128;
    const int hoff = h * DK;

    bf16x8 qf[2][2];
#pragma unroll
    for (int t = 0; t < 2; t++)
#pragma unroll
        for (int c = 0; c < 2; c++)
            qf[t][c] = *(const bf16x8*)(Q + (size_t)(q0 + wave * 32 + t * 16 + l15) * D_MODEL
                                        + hoff + c * 32 + lg * 8);

    f32x4 oacc[2][4], lfrag[2];
#pragma unroll
    for (int t = 0; t < 2; t++) {
        lfrag[t] = f32x4{0.f, 0.f, 0.f, 0.f};
#pragma unroll
        for (int dt = 0; dt < 4; dt++) oacc[t][dt] = f32x4{0.f, 0.f, 0.f, 0.f};
    }

    bf16x8 ones8;
#pragma unroll
    for (int j = 0; j < 8; j++) ones8[j] = (bf16_t)1.0f;

    // per-lane global fragment bases (coalesced: 16 rows x 64B lines per load)
    const bf16_t* kB = Km + (size_t)l15 * D_MODEL + hoff + lg * 8;
    const bf16_t* vB = Vt + (size_t)(hoff + l15) * SEQ + lg * 8;

    Frags fA, fB;
    load_frags(fA, kB, vB, 0);

    for (int s = 0; s < SEQ / 64; s += 2) {
        load_frags(fB, kB, vB, s + 1);
        compute_step(fA, qf, oacc, lfrag, ones8);
        if (s + 2 < SEQ / 64) load_frags(fA, kB, vB, s + 2);
        compute_step(fB, qf, oacc, lfrag, ones8);
    }

    // direct store: col = query (lane-local l), row band = d
#pragma unroll
    for (int t = 0; t < 2; t++) {
        const float inv = 1.f / lfrag[t][0];
        const size_t qrow = (size_t)(q0 + wave * 32 + t * 16 + l15);
#pragma unroll
        for (int dt = 0; dt < 4; dt++) {
            bf16x4 o4;
#pragma unroll
            for (int r = 0; r < 4; r++) o4[r] = (bf16_t)(oacc[t][dt][r] * inv);
            *(bf16x4*)(O + qrow * D_MODEL + hoff + dt * 16 + lg * 4) = o4;
        }
    }
}

// ---------------- launcher ----------------
extern "C" void kernel_launch(void* const* d_in, const int* in_sizes, int n_in,
                              void* d_out, int out_size, void* d_ws, size_t ws_size,
                              hipStream_t stream) {
    const float* x  = (const float*)d_in[0];
    const float* Wq = (const float*)d_in[1];
    const float* Wk = (const float*)d_in[2];
    const float* Wv = (const float*)d_in[3];
    const float* Wo = (const float*)d_in[4];
    float* out = (float*)d_out;

    char* ws = (char*)d_ws;
    bf16_t* xb  = (bf16_t*)(ws);
    bf16_t* wqb = (bf16_t*)(ws + (8u  << 20));
    bf16_t* wob = (bf16_t*)(ws + (14u << 20));
    bf16_t* Qb  = (bf16_t*)(ws + (16u << 20));
    bf16_t* Kb  = (bf16_t*)(ws + (24u << 20));
    bf16_t* Vtb = (bf16_t*)(ws + (32u << 20));
    bf16_t* Ab  = (bf16_t*)(ws + (40u << 20));

    const int nX = SEQ * D_MODEL;
    cast_kernel<<<nX / 4 / 256, 256, 0, stream>>>(x, xb, nX);
    cast4_kernel<<<4 * 1024, 256, 0, stream>>>(Wq, Wk, Wv, Wo, wqb);

    gemm_lds<1><<<dim3(3 * D_MODEL / 64, SEQ / 128), 256, 0, stream>>>(
        xb, wqb, Qb, Kb, Vtb, SEQ, 3 * D_MODEL, D_MODEL);

    attn_kernel<<<512, 256, 0, stream>>>(Qb, Kb, Vtb, Ab);

    gemm_lds<0><<<dim3(D_MODEL / 64, SEQ / 128), 256, 0, stream>>>(
        Ab, wob, out, nullptr, nullptr, SEQ, D_MODEL, D_MODEL);
}

// Round 3
// 200.072 us; speedup vs baseline: 1.7808x; 1.7808x over previous
//
#include <hip/hip_runtime.h>
#include <hip/hip_bf16.h>

// MHA block: x[4096,1024] fp32; Wq/Wk/Wv/Wo [1024,1024] fp32.
// R13: attention LDS-redundancy cut.
//  R10 pipe audit: per CU-step LDS=1536cyc (44%, 8 waves all reading the
//  SAME K/V fragments), MFMA=1382 (39%), VALU~50% -> pipes sum to wall,
//  no overlap. LDS reads/wave/step are constant in q-rows, so each wave now
//  owns 64 q-rows (4 waves x 64 = 256-row q-block, grid 256 = 1 block/CU):
//  halves per-FLOP LDS traffic and amortizes per-step VALU overhead 2x.
//  Epilogue = R12 direct store (no Ot union, no final barrier).
//  R12 lesson: reg-staged direct-global collapses (compiler can't hold 128
//  VGPRs of frags -> serializes); g2l16+LDS dbuf skeleton restored verbatim.
// Keeps: R10 sync skeleton (1 barrier/step, prefetch-then-compute),
//  magic-mantissa Schraudolph exp2 (proven R12), S^T trick, MFMA l-sums,
//  key-interleaved V^T, R6 GEMMs/casts.

typedef __bf16 bf16_t;
typedef __bf16 bf16x8 __attribute__((ext_vector_type(8)));
typedef __bf16 bf16x4 __attribute__((ext_vector_type(4)));
typedef float f32x4 __attribute__((ext_vector_type(4)));

#define D_MODEL 1024
#define SEQ 4096
#define HEADS 16
#define DK 64
#define QSCALE 0.1803368801111204f  // log2(e)/8
#define EXP2_MAGIC 8404859.0f       // 2^23 + 16251 (integer-exact float)

// ---------------- casts fp32 -> bf16 ----------------
__global__ void cast_kernel(const float* __restrict__ in, bf16_t* __restrict__ out, int n) {
    int i = (blockIdx.x * blockDim.x + threadIdx.x) * 4;
    if (i < n) {
        float4 v = *(const float4*)(in + i);
        bf16x4 o;
        o[0] = (bf16_t)v.x; o[1] = (bf16_t)v.y; o[2] = (bf16_t)v.z; o[3] = (bf16_t)v.w;
        *(bf16x4*)(out + i) = o;
    }
}

__global__ void cast4_kernel(const float* __restrict__ a, const float* __restrict__ b,
                             const float* __restrict__ c, const float* __restrict__ d,
                             bf16_t* __restrict__ out) {
    int gi = blockIdx.x * blockDim.x + threadIdx.x;
    int which = gi >> 18;
    int i = (gi & 0x3FFFF) * 4;
    const float* src = which == 0 ? a : which == 1 ? b : which == 2 ? c : d;
    float4 v = *(const float4*)(src + i);
    bf16x4 o;
    o[0] = (bf16_t)v.x; o[1] = (bf16_t)v.y; o[2] = (bf16_t)v.z; o[3] = (bf16_t)v.w;
    *(bf16x4*)(out + (size_t)which * D_MODEL * D_MODEL + i) = o;
}

__device__ __forceinline__ void g2l16(const bf16_t* g, bf16_t* l) {
    __builtin_amdgcn_global_load_lds(
        (const __attribute__((address_space(1))) void*)g,
        (__attribute__((address_space(3))) void*)l, 16, 0, 0);
}

// Schraudolph exp2 -> packed bf16x8: slots 0-3 = 2^a[r], 4-7 = 2^b[r].
// fma into [2^23,2^24): low 16 float bits ARE the bf16 bits; v_perm packs.
__device__ __forceinline__ bf16x8 exp2_pk(const f32x4 a, const f32x4 b) {
    union { float f; unsigned u; } v[8];
#pragma unroll
    for (int r = 0; r < 4; r++) {
        v[r].f     = fmaf(a[r], 128.0f, EXP2_MAGIC);
        v[r + 4].f = fmaf(b[r], 128.0f, EXP2_MAGIC);
    }
    union { unsigned u[4]; bf16x8 h; } o;
#pragma unroll
    for (int p = 0; p < 4; p++)
        o.u[p] = __builtin_amdgcn_perm(v[2 * p + 1].u, v[2 * p].u, 0x05040100u);
    return o.h;
}

// ---------------- LDS-staged NT GEMM ----------------
// ROUTE 1: QKV split; V^T written key-interleaved (see header comment).
template <int ROUTE>
__global__ __launch_bounds__(256, 4) void gemm_lds(const bf16_t* __restrict__ A,
                                                   const bf16_t* __restrict__ B,
                                                   void* __restrict__ out0,
                                                   void* __restrict__ out1,
                                                   void* __restrict__ out2,
                                                   int M, int N, int K) {
    __shared__ __align__(16) bf16_t As[128 * 64];
    __shared__ __align__(16) bf16_t Bs[64 * 64];

    const int tid = threadIdx.x;
    const int lane = tid & 63;
    const int wave = tid >> 6;
    const int l15 = lane & 15;
    const int lg  = lane >> 4;
    const int m0 = blockIdx.y * 128;
    const int n0 = blockIdx.x * 64;
    const int wm = (wave >> 1) * 64;
    const int wn = (wave & 1) * 32;

    const bf16_t* aSrc[4]; bf16_t* aDst[4];
#pragma unroll
    for (int it = 0; it < 4; it++) {
        int c = it * 256 + tid;
        int row = c >> 3, cc = (c & 7) ^ (row & 7);
        aSrc[it] = A + (size_t)(m0 + row) * K + cc * 8;
        aDst[it] = As + c * 8;
    }
    const bf16_t* bSrc[2]; bf16_t* bDst[2];
#pragma unroll
    for (int it = 0; it < 2; it++) {
        int c = it * 256 + tid;
        int row = c >> 3, cc = (c & 7) ^ (row & 7);
        bSrc[it] = B + (size_t)(n0 + row) * K + cc * 8;
        bDst[it] = Bs + c * 8;
    }

    int aoff[2][4], boff[2][2];
#pragma unroll
    for (int kk = 0; kk < 2; kk++) {
#pragma unroll
        for (int i = 0; i < 4; i++) {
            int row = wm + i * 16 + l15;
            aoff[kk][i] = row * 64 + (((kk << 2) | lg) ^ (row & 7)) * 8;
        }
#pragma unroll
        for (int j = 0; j < 2; j++) {
            int row = wn + j * 16 + l15;
            boff[kk][j] = row * 64 + (((kk << 2) | lg) ^ (row & 7)) * 8;
        }
    }

    f32x4 acc[4][2];
#pragma unroll
    for (int i = 0; i < 4; i++)
#pragma unroll
        for (int j = 0; j < 2; j++) acc[i][j] = f32x4{0.f, 0.f, 0.f, 0.f};

    for (int k0 = 0; k0 < K; k0 += 64) {
#pragma unroll
        for (int it = 0; it < 4; it++) g2l16(aSrc[it] + k0, aDst[it]);
#pragma unroll
        for (int it = 0; it < 2; it++) g2l16(bSrc[it] + k0, bDst[it]);
        __syncthreads();

#pragma unroll
        for (int kk = 0; kk < 2; kk++) {
            bf16x8 af[4], bfm[2];
#pragma unroll
            for (int i = 0; i < 4; i++) af[i] = *(const bf16x8*)(As + aoff[kk][i]);
#pragma unroll
            for (int j = 0; j < 2; j++) bfm[j] = *(const bf16x8*)(Bs + boff[kk][j]);
#pragma unroll
            for (int i = 0; i < 4; i++)
#pragma unroll
                for (int j = 0; j < 2; j++)
                    acc[i][j] = __builtin_amdgcn_mfma_f32_16x16x32_bf16(af[i], bfm[j], acc[i][j], 0, 0, 0);
        }
        __syncthreads();
    }

    const int ng = n0 + wn;
    if (ROUTE == 0) {
        float* C = (float*)out0;
#pragma unroll
        for (int i = 0; i < 4; i++)
#pragma unroll
            for (int r = 0; r < 4; r++) {
                int m = m0 + wm + i * 16 + lg * 4 + r;
                float* crow = C + (size_t)m * N + ng;
#pragma unroll
                for (int j = 0; j < 2; j++) crow[j * 16 + l15] = acc[i][j][r];
            }
    } else {
        if (ng < 2048) {
            const bool isQ = (ng < 1024);
            const float sc = isQ ? QSCALE : 1.0f;
            bf16_t* dst = isQ ? (bf16_t*)out0 : (bf16_t*)out1;
            int nn = ng & 1023;
#pragma unroll
            for (int i = 0; i < 4; i++)
#pragma unroll
                for (int r = 0; r < 4; r++) {
                    int m = m0 + wm + i * 16 + lg * 4 + r;
                    bf16_t* crow = dst + (size_t)m * D_MODEL + nn;
#pragma unroll
                    for (int j = 0; j < 2; j++) crow[j * 16 + l15] = (bf16_t)(acc[i][j][r] * sc);
                }
        } else {
            bf16_t* Vt = (bf16_t*)out2;
#pragma unroll
            for (int i = 0; i < 4; i++)
#pragma unroll
                for (int j = 0; j < 2; j++) {
                    int vcol = ng - 2048 + j * 16 + l15;
                    int m = m0 + wm + i * 16 + lg * 4;  // multiple of 4
                    // key-interleave within 32-key block: pos = g*8 + sub*4 + r
                    int mp = (m & ~31) | (((m >> 2) & 3) << 3) | (((m >> 4) & 1) << 2);
                    bf16x4 v4;
#pragma unroll
                    for (int r = 0; r < 4; r++) v4[r] = (bf16_t)acc[i][j][r];
                    *(bf16x4*)(Vt + (size_t)vcol * SEQ + mp) = v4;
                }
        }
    }
}

// -------- attention: 4 waves x 64 q-rows, LDS dbuf, direct store ----------
__global__ __launch_bounds__(256, 1) void attn_kernel(const bf16_t* __restrict__ Q,
                                                      const bf16_t* __restrict__ Km,
                                                      const bf16_t* __restrict__ Vt,
                                                      bf16_t* __restrict__ O) {
    const int tid = threadIdx.x;
    const int lane = tid & 63;
    const int wave = tid >> 6;   // 0..3, each owns 64 q-rows
    const int l15 = lane & 15;
    const int lg  = lane >> 4;
    const int bid = blockIdx.x;
    const int h    = (bid & 7) * 2 + ((bid >> 3) & 1);  // 2 heads/XCD -> K/V L2-resident
    const int qblk = bid >> 4;   // 0..15
    const int q0 = qblk * 256;
    const int hoff = h * DK;

    __shared__ struct {
        __align__(16) bf16_t K[2][64 * 64];
        __align__(16) bf16_t V[2][64 * 64];
    } sm;

    bf16x8 qf[4][2];
#pragma unroll
    for (int t = 0; t < 4; t++)
#pragma unroll
        for (int c = 0; c < 2; c++)
            qf[t][c] = *(const bf16x8*)(Q + (size_t)(q0 + wave * 64 + t * 16 + l15) * D_MODEL
                                        + hoff + c * 32 + lg * 8);

    f32x4 oacc[4][4], lfrag[4];
#pragma unroll
    for (int t = 0; t < 4; t++) {
        lfrag[t] = f32x4{0.f, 0.f, 0.f, 0.f};
#pragma unroll
        for (int dt = 0; dt < 4; dt++) oacc[t][dt] = f32x4{0.f, 0.f, 0.f, 0.f};
    }

    bf16x8 ones8;
#pragma unroll
    for (int j = 0; j < 8; j++) ones8[j] = (bf16_t)1.0f;

    const bf16_t* kSrc[2]; const bf16_t* vSrc[2];
#pragma unroll
    for (int it = 0; it < 2; it++) {
        int c = it * 256 + tid;
        int row = c >> 3, dc = (c & 7) ^ (row & 7);
        kSrc[it] = Km + (size_t)row * D_MODEL + hoff + dc * 8;
        vSrc[it] = Vt + (size_t)(hoff + row) * SEQ + dc * 8;
    }

    int kOff[4][2], vOff[2][4];
#pragma unroll
    for (int kt = 0; kt < 4; kt++)
#pragma unroll
        for (int c = 0; c < 2; c++) {
            int row = kt * 16 + l15;
            kOff[kt][c] = row * 64 + (((c * 4 + lg) ^ (row & 7)) * 8);
        }
#pragma unroll
    for (int kp = 0; kp < 2; kp++)
#pragma unroll
        for (int dt = 0; dt < 4; dt++) {
            int row = dt * 16 + l15;
            // single b128: interleaved keys, column kp*32 + lg*8
            vOff[kp][dt] = row * 64 + (((kp * 4 + lg) ^ (row & 7)) * 8);
        }

    // prologue: stage step 0 into buffer 0
#pragma unroll
    for (int it = 0; it < 2; it++) {
        g2l16(kSrc[it], &sm.K[0][(it * 256 + tid) * 8]);
        g2l16(vSrc[it], &sm.V[0][(it * 256 + tid) * 8]);
    }

    for (int s = 0; s < SEQ / 64; s++) {
        const int cur = s & 1;
        __syncthreads();

        if (s + 1 < SEQ / 64) {
            const int nxt = cur ^ 1;
#pragma unroll
            for (int it = 0; it < 2; it++) {
                g2l16(kSrc[it] + (size_t)(s + 1) * 64 * D_MODEL, &sm.K[nxt][(it * 256 + tid) * 8]);
                g2l16(vSrc[it] + (s + 1) * 64,                   &sm.V[nxt][(it * 256 + tid) * 8]);
            }
        }

        const bf16_t* Kb = sm.K[cur];
        const bf16_t* Vb = sm.V[cur];

#pragma unroll
        for (int kp = 0; kp < 2; kp++) {
            bf16x8 vf[4];
#pragma unroll
            for (int dt = 0; dt < 4; dt++) vf[dt] = *(const bf16x8*)(Vb + vOff[kp][dt]);

            f32x4 st[4][2];
#pragma unroll
            for (int sub = 0; sub < 2; sub++) {
                const int kt = kp * 2 + sub;
                const bf16x8 kf0 = *(const bf16x8*)(Kb + kOff[kt][0]);
                const bf16x8 kf1 = *(const bf16x8*)(Kb + kOff[kt][1]);
#pragma unroll
                for (int t = 0; t < 4; t++) {
                    f32x4 a = f32x4{0.f, 0.f, 0.f, 0.f};
                    a = __builtin_amdgcn_mfma_f32_16x16x32_bf16(kf0, qf[t][0], a, 0, 0, 0);
                    a = __builtin_amdgcn_mfma_f32_16x16x32_bf16(kf1, qf[t][1], a, 0, 0, 0);
                    st[t][sub] = a;
                }
            }

#pragma unroll
            for (int t = 0; t < 4; t++) {
                const bf16x8 pbig = exp2_pk(st[t][0], st[t][1]);
                lfrag[t] = __builtin_amdgcn_mfma_f32_16x16x32_bf16(ones8, pbig, lfrag[t], 0, 0, 0);
#pragma unroll
                for (int dt = 0; dt < 4; dt++)
                    oacc[t][dt] = __builtin_amdgcn_mfma_f32_16x16x32_bf16(vf[dt], pbig, oacc[t][dt], 0, 0, 0);
            }
        }
    }

    // direct store: col = query (lane-local l), row band = d
#pragma unroll
    for (int t = 0; t < 4; t++) {
        const float inv = 1.f / lfrag[t][0];
        const size_t qrow = (size_t)(q0 + wave * 64 + t * 16 + l15);
#pragma unroll
        for (int dt = 0; dt < 4; dt++) {
            bf16x4 o4;
#pragma unroll
            for (int r = 0; r < 4; r++) o4[r] = (bf16_t)(oacc[t][dt][r] * inv);
            *(bf16x4*)(O + qrow * D_MODEL + hoff + dt * 16 + lg * 4) = o4;
        }
    }
}

// ---------------- launcher ----------------
extern "C" void kernel_launch(void* const* d_in, const int* in_sizes, int n_in,
                              void* d_out, int out_size, void* d_ws, size_t ws_size,
                              hipStream_t stream) {
    const float* x  = (const float*)d_in[0];
    const float* Wq = (const float*)d_in[1];
    const float* Wk = (const float*)d_in[2];
    const float* Wv = (const float*)d_in[3];
    const float* Wo = (const float*)d_in[4];
    float* out = (float*)d_out;

    char* ws = (char*)d_ws;
    bf16_t* xb  = (bf16_t*)(ws);
    bf16_t* wqb = (bf16_t*)(ws + (8u  << 20));
    bf16_t* wob = (bf16_t*)(ws + (14u << 20));
    bf16_t* Qb  = (bf16_t*)(ws + (16u << 20));
    bf16_t* Kb  = (bf16_t*)(ws + (24u << 20));
    bf16_t* Vtb = (bf16_t*)(ws + (32u << 20));
    bf16_t* Ab  = (bf16_t*)(ws + (40u << 20));

    const int nX = SEQ * D_MODEL;
    cast_kernel<<<nX / 4 / 256, 256, 0, stream>>>(x, xb, nX);
    cast4_kernel<<<4 * 1024, 256, 0, stream>>>(Wq, Wk, Wv, Wo, wqb);

    gemm_lds<1><<<dim3(3 * D_MODEL / 64, SEQ / 128), 256, 0, stream>>>(
        xb, wqb, Qb, Kb, Vtb, SEQ, 3 * D_MODEL, D_MODEL);

    attn_kernel<<<256, 256, 0, stream>>>(Qb, Kb, Vtb, Ab);

    gemm_lds<0><<<dim3(D_MODEL / 64, SEQ / 128), 256, 0, stream>>>(
        Ab, wob, out, nullptr, nullptr, SEQ, D_MODEL, D_MODEL);
}

// Round 4
// 190.893 us; speedup vs baseline: 1.8664x; 1.0481x over previous
//
#include <hip/hip_runtime.h>
#include <hip/hip_bf16.h>

// MHA block: x[4096,1024] fp32; Wq/Wk/Wv/Wo [1024,1024] fp32.
// R14: attention TLP restore — 8 waves x 32 q-rows (512 thr), grid 256.
//  R13 audit (corrected): per-SIMD MFMA floor = 72 mfma/step x ~19 cyc =
//  1397 cyc vs 3000 cyc wall at 1 wave/SIMD -> 54% of wall is dependency
//  stall (MfmaUtil 40%, Occ 10%). VALUBusy ~= MfmaUtil + ~8% (derived
//  counter includes matrix pipe) -> exp diet already sufficient.
//  Fix: same 256-row q-block split 8 ways instead of 4 -> 2 waves/SIMD
//  fill each other's QK->exp->PV latency gaps. MFMA + true-VALU per CU
//  unchanged; LDS reads/CU-step double (128 b128 ~ 500-1500 cyc CU-pipe,
//  still under the MFMA floor). vs R11's failed 512-thr attempt: keeps
//  R13's proven dbuf struct (no union), direct-global epilogue (no LDS,
//  no tail barrier), identical per-step barrier skeleton.
// Keeps: magic-mantissa Schraudolph exp2, S^T trick, MFMA l-sums,
//  key-interleaved V^T, R6 GEMMs/casts.

typedef __bf16 bf16_t;
typedef __bf16 bf16x8 __attribute__((ext_vector_type(8)));
typedef __bf16 bf16x4 __attribute__((ext_vector_type(4)));
typedef float f32x4 __attribute__((ext_vector_type(4)));

#define D_MODEL 1024
#define SEQ 4096
#define HEADS 16
#define DK 64
#define QSCALE 0.1803368801111204f  // log2(e)/8
#define EXP2_MAGIC 8404859.0f       // 2^23 + 16251 (integer-exact float)

// ---------------- casts fp32 -> bf16 ----------------
__global__ void cast_kernel(const float* __restrict__ in, bf16_t* __restrict__ out, int n) {
    int i = (blockIdx.x * blockDim.x + threadIdx.x) * 4;
    if (i < n) {
        float4 v = *(const float4*)(in + i);
        bf16x4 o;
        o[0] = (bf16_t)v.x; o[1] = (bf16_t)v.y; o[2] = (bf16_t)v.z; o[3] = (bf16_t)v.w;
        *(bf16x4*)(out + i) = o;
    }
}

__global__ void cast4_kernel(const float* __restrict__ a, const float* __restrict__ b,
                             const float* __restrict__ c, const float* __restrict__ d,
                             bf16_t* __restrict__ out) {
    int gi = blockIdx.x * blockDim.x + threadIdx.x;
    int which = gi >> 18;
    int i = (gi & 0x3FFFF) * 4;
    const float* src = which == 0 ? a : which == 1 ? b : which == 2 ? c : d;
    float4 v = *(const float4*)(src + i);
    bf16x4 o;
    o[0] = (bf16_t)v.x; o[1] = (bf16_t)v.y; o[2] = (bf16_t)v.z; o[3] = (bf16_t)v.w;
    *(bf16x4*)(out + (size_t)which * D_MODEL * D_MODEL + i) = o;
}

__device__ __forceinline__ void g2l16(const bf16_t* g, bf16_t* l) {
    __builtin_amdgcn_global_load_lds(
        (const __attribute__((address_space(1))) void*)g,
        (__attribute__((address_space(3))) void*)l, 16, 0, 0);
}

// Schraudolph exp2 -> packed bf16x8: slots 0-3 = 2^a[r], 4-7 = 2^b[r].
// fma into [2^23,2^24): low 16 float bits ARE the bf16 bits; v_perm packs.
__device__ __forceinline__ bf16x8 exp2_pk(const f32x4 a, const f32x4 b) {
    union { float f; unsigned u; } v[8];
#pragma unroll
    for (int r = 0; r < 4; r++) {
        v[r].f     = fmaf(a[r], 128.0f, EXP2_MAGIC);
        v[r + 4].f = fmaf(b[r], 128.0f, EXP2_MAGIC);
    }
    union { unsigned u[4]; bf16x8 h; } o;
#pragma unroll
    for (int p = 0; p < 4; p++)
        o.u[p] = __builtin_amdgcn_perm(v[2 * p + 1].u, v[2 * p].u, 0x05040100u);
    return o.h;
}

// ---------------- LDS-staged NT GEMM ----------------
// ROUTE 1: QKV split; V^T written key-interleaved (see header comment).
template <int ROUTE>
__global__ __launch_bounds__(256, 4) void gemm_lds(const bf16_t* __restrict__ A,
                                                   const bf16_t* __restrict__ B,
                                                   void* __restrict__ out0,
                                                   void* __restrict__ out1,
                                                   void* __restrict__ out2,
                                                   int M, int N, int K) {
    __shared__ __align__(16) bf16_t As[128 * 64];
    __shared__ __align__(16) bf16_t Bs[64 * 64];

    const int tid = threadIdx.x;
    const int lane = tid & 63;
    const int wave = tid >> 6;
    const int l15 = lane & 15;
    const int lg  = lane >> 4;
    const int m0 = blockIdx.y * 128;
    const int n0 = blockIdx.x * 64;
    const int wm = (wave >> 1) * 64;
    const int wn = (wave & 1) * 32;

    const bf16_t* aSrc[4]; bf16_t* aDst[4];
#pragma unroll
    for (int it = 0; it < 4; it++) {
        int c = it * 256 + tid;
        int row = c >> 3, cc = (c & 7) ^ (row & 7);
        aSrc[it] = A + (size_t)(m0 + row) * K + cc * 8;
        aDst[it] = As + c * 8;
    }
    const bf16_t* bSrc[2]; bf16_t* bDst[2];
#pragma unroll
    for (int it = 0; it < 2; it++) {
        int c = it * 256 + tid;
        int row = c >> 3, cc = (c & 7) ^ (row & 7);
        bSrc[it] = B + (size_t)(n0 + row) * K + cc * 8;
        bDst[it] = Bs + c * 8;
    }

    int aoff[2][4], boff[2][2];
#pragma unroll
    for (int kk = 0; kk < 2; kk++) {
#pragma unroll
        for (int i = 0; i < 4; i++) {
            int row = wm + i * 16 + l15;
            aoff[kk][i] = row * 64 + (((kk << 2) | lg) ^ (row & 7)) * 8;
        }
#pragma unroll
        for (int j = 0; j < 2; j++) {
            int row = wn + j * 16 + l15;
            boff[kk][j] = row * 64 + (((kk << 2) | lg) ^ (row & 7)) * 8;
        }
    }

    f32x4 acc[4][2];
#pragma unroll
    for (int i = 0; i < 4; i++)
#pragma unroll
        for (int j = 0; j < 2; j++) acc[i][j] = f32x4{0.f, 0.f, 0.f, 0.f};

    for (int k0 = 0; k0 < K; k0 += 64) {
#pragma unroll
        for (int it = 0; it < 4; it++) g2l16(aSrc[it] + k0, aDst[it]);
#pragma unroll
        for (int it = 0; it < 2; it++) g2l16(bSrc[it] + k0, bDst[it]);
        __syncthreads();

#pragma unroll
        for (int kk = 0; kk < 2; kk++) {
            bf16x8 af[4], bfm[2];
#pragma unroll
            for (int i = 0; i < 4; i++) af[i] = *(const bf16x8*)(As + aoff[kk][i]);
#pragma unroll
            for (int j = 0; j < 2; j++) bfm[j] = *(const bf16x8*)(Bs + boff[kk][j]);
#pragma unroll
            for (int i = 0; i < 4; i++)
#pragma unroll
                for (int j = 0; j < 2; j++)
                    acc[i][j] = __builtin_amdgcn_mfma_f32_16x16x32_bf16(af[i], bfm[j], acc[i][j], 0, 0, 0);
        }
        __syncthreads();
    }

    const int ng = n0 + wn;
    if (ROUTE == 0) {
        float* C = (float*)out0;
#pragma unroll
        for (int i = 0; i < 4; i++)
#pragma unroll
            for (int r = 0; r < 4; r++) {
                int m = m0 + wm + i * 16 + lg * 4 + r;
                float* crow = C + (size_t)m * N + ng;
#pragma unroll
                for (int j = 0; j < 2; j++) crow[j * 16 + l15] = acc[i][j][r];
            }
    } else {
        if (ng < 2048) {
            const bool isQ = (ng < 1024);
            const float sc = isQ ? QSCALE : 1.0f;
            bf16_t* dst = isQ ? (bf16_t*)out0 : (bf16_t*)out1;
            int nn = ng & 1023;
#pragma unroll
            for (int i = 0; i < 4; i++)
#pragma unroll
                for (int r = 0; r < 4; r++) {
                    int m = m0 + wm + i * 16 + lg * 4 + r;
                    bf16_t* crow = dst + (size_t)m * D_MODEL + nn;
#pragma unroll
                    for (int j = 0; j < 2; j++) crow[j * 16 + l15] = (bf16_t)(acc[i][j][r] * sc);
                }
        } else {
            bf16_t* Vt = (bf16_t*)out2;
#pragma unroll
            for (int i = 0; i < 4; i++)
#pragma unroll
                for (int j = 0; j < 2; j++) {
                    int vcol = ng - 2048 + j * 16 + l15;
                    int m = m0 + wm + i * 16 + lg * 4;  // multiple of 4
                    // key-interleave within 32-key block: pos = g*8 + sub*4 + r
                    int mp = (m & ~31) | (((m >> 2) & 3) << 3) | (((m >> 4) & 1) << 2);
                    bf16x4 v4;
#pragma unroll
                    for (int r = 0; r < 4; r++) v4[r] = (bf16_t)acc[i][j][r];
                    *(bf16x4*)(Vt + (size_t)vcol * SEQ + mp) = v4;
                }
        }
    }
}

// ---- attention: 8 waves x 32 q-rows, LDS dbuf, direct store, grid 256 ----
__global__ __launch_bounds__(512, 2) void attn_kernel(const bf16_t* __restrict__ Q,
                                                      const bf16_t* __restrict__ Km,
                                                      const bf16_t* __restrict__ Vt,
                                                      bf16_t* __restrict__ O) {
    const int tid = threadIdx.x;
    const int lane = tid & 63;
    const int wave = tid >> 6;   // 0..7, each owns 32 q-rows
    const int l15 = lane & 15;
    const int lg  = lane >> 4;
    const int bid = blockIdx.x;
    const int h    = (bid & 7) * 2 + ((bid >> 3) & 1);  // 2 heads/XCD -> K/V L2-resident
    const int qblk = bid >> 4;   // 0..15
    const int q0 = qblk * 256;
    const int hoff = h * DK;

    __shared__ struct {
        __align__(16) bf16_t K[2][64 * 64];
        __align__(16) bf16_t V[2][64 * 64];
    } sm;

    bf16x8 qf[2][2];
#pragma unroll
    for (int t = 0; t < 2; t++)
#pragma unroll
        for (int c = 0; c < 2; c++)
            qf[t][c] = *(const bf16x8*)(Q + (size_t)(q0 + wave * 32 + t * 16 + l15) * D_MODEL
                                        + hoff + c * 32 + lg * 8);

    f32x4 oacc[2][4], lfrag[2];
#pragma unroll
    for (int t = 0; t < 2; t++) {
        lfrag[t] = f32x4{0.f, 0.f, 0.f, 0.f};
#pragma unroll
        for (int dt = 0; dt < 4; dt++) oacc[t][dt] = f32x4{0.f, 0.f, 0.f, 0.f};
    }

    bf16x8 ones8;
#pragma unroll
    for (int j = 0; j < 8; j++) ones8[j] = (bf16_t)1.0f;

    // staging: 512 threads x one 16B chunk per tile (64x64 bf16 = 8KB each)
    const int srow = tid >> 3;
    const int sdc = (tid & 7) ^ (srow & 7);
    const bf16_t* kSrc = Km + (size_t)srow * D_MODEL + hoff + sdc * 8;
    const bf16_t* vSrc = Vt + (size_t)(hoff + srow) * SEQ + sdc * 8;

    int kOff[4][2], vOff[2][4];
#pragma unroll
    for (int kt = 0; kt < 4; kt++)
#pragma unroll
        for (int c = 0; c < 2; c++) {
            int row = kt * 16 + l15;
            kOff[kt][c] = row * 64 + (((c * 4 + lg) ^ (row & 7)) * 8);
        }
#pragma unroll
    for (int kp = 0; kp < 2; kp++)
#pragma unroll
        for (int dt = 0; dt < 4; dt++) {
            int row = dt * 16 + l15;
            // single b128: interleaved keys, column kp*32 + lg*8
            vOff[kp][dt] = row * 64 + (((kp * 4 + lg) ^ (row & 7)) * 8);
        }

    // prologue: stage step 0 into buffer 0
    g2l16(kSrc, &sm.K[0][tid * 8]);
    g2l16(vSrc, &sm.V[0][tid * 8]);

    for (int s = 0; s < SEQ / 64; s++) {
        const int cur = s & 1;
        __syncthreads();

        if (s + 1 < SEQ / 64) {
            const int nxt = cur ^ 1;
            g2l16(kSrc + (size_t)(s + 1) * 64 * D_MODEL, &sm.K[nxt][tid * 8]);
            g2l16(vSrc + (s + 1) * 64,                   &sm.V[nxt][tid * 8]);
        }

        const bf16_t* Kb = sm.K[cur];
        const bf16_t* Vb = sm.V[cur];

#pragma unroll
        for (int kp = 0; kp < 2; kp++) {
            bf16x8 vf[4];
#pragma unroll
            for (int dt = 0; dt < 4; dt++) vf[dt] = *(const bf16x8*)(Vb + vOff[kp][dt]);

            f32x4 st[2][2];
#pragma unroll
            for (int sub = 0; sub < 2; sub++) {
                const int kt = kp * 2 + sub;
                const bf16x8 kf0 = *(const bf16x8*)(Kb + kOff[kt][0]);
                const bf16x8 kf1 = *(const bf16x8*)(Kb + kOff[kt][1]);
#pragma unroll
                for (int t = 0; t < 2; t++) {
                    f32x4 a = f32x4{0.f, 0.f, 0.f, 0.f};
                    a = __builtin_amdgcn_mfma_f32_16x16x32_bf16(kf0, qf[t][0], a, 0, 0, 0);
                    a = __builtin_amdgcn_mfma_f32_16x16x32_bf16(kf1, qf[t][1], a, 0, 0, 0);
                    st[t][sub] = a;
                }
            }

#pragma unroll
            for (int t = 0; t < 2; t++) {
                const bf16x8 pbig = exp2_pk(st[t][0], st[t][1]);
                lfrag[t] = __builtin_amdgcn_mfma_f32_16x16x32_bf16(ones8, pbig, lfrag[t], 0, 0, 0);
#pragma unroll
                for (int dt = 0; dt < 4; dt++)
                    oacc[t][dt] = __builtin_amdgcn_mfma_f32_16x16x32_bf16(vf[dt], pbig, oacc[t][dt], 0, 0, 0);
            }
        }
    }

    // direct store: col = query (lane-local l), row band = d
#pragma unroll
    for (int t = 0; t < 2; t++) {
        const float inv = 1.f / lfrag[t][0];
        const size_t qrow = (size_t)(q0 + wave * 32 + t * 16 + l15);
#pragma unroll
        for (int dt = 0; dt < 4; dt++) {
            bf16x4 o4;
#pragma unroll
            for (int r = 0; r < 4; r++) o4[r] = (bf16_t)(oacc[t][dt][r] * inv);
            *(bf16x4*)(O + qrow * D_MODEL + hoff + dt * 16 + lg * 4) = o4;
        }
    }
}

// ---------------- launcher ----------------
extern "C" void kernel_launch(void* const* d_in, const int* in_sizes, int n_in,
                              void* d_out, int out_size, void* d_ws, size_t ws_size,
                              hipStream_t stream) {
    const float* x  = (const float*)d_in[0];
    const float* Wq = (const float*)d_in[1];
    const float* Wk = (const float*)d_in[2];
    const float* Wv = (const float*)d_in[3];
    const float* Wo = (const float*)d_in[4];
    float* out = (float*)d_out;

    char* ws = (char*)d_ws;
    bf16_t* xb  = (bf16_t*)(ws);
    bf16_t* wqb = (bf16_t*)(ws + (8u  << 20));
    bf16_t* wob = (bf16_t*)(ws + (14u << 20));
    bf16_t* Qb  = (bf16_t*)(ws + (16u << 20));
    bf16_t* Kb  = (bf16_t*)(ws + (24u << 20));
    bf16_t* Vtb = (bf16_t*)(ws + (32u << 20));
    bf16_t* Ab  = (bf16_t*)(ws + (40u << 20));

    const int nX = SEQ * D_MODEL;
    cast_kernel<<<nX / 4 / 256, 256, 0, stream>>>(x, xb, nX);
    cast4_kernel<<<4 * 1024, 256, 0, stream>>>(Wq, Wk, Wv, Wo, wqb);

    gemm_lds<1><<<dim3(3 * D_MODEL / 64, SEQ / 128), 256, 0, stream>>>(
        xb, wqb, Qb, Kb, Vtb, SEQ, 3 * D_MODEL, D_MODEL);

    attn_kernel<<<256, 512, 0, stream>>>(Qb, Kb, Vtb, Ab);

    gemm_lds<0><<<dim3(D_MODEL / 64, SEQ / 128), 256, 0, stream>>>(
        Ab, wob, out, nullptr, nullptr, SEQ, D_MODEL, D_MODEL);
}